// Round 7
// baseline (315.521 us; speedup 1.0000x reference)
//
#include <hip/hip_runtime.h>
#include <hip/hip_fp16.h>

#define NN 50000
#define NE 800000
#define D 128
#define NBLK ((NN + 255) / 256)   // 196 blocks over nodes

typedef __attribute__((ext_vector_type(8))) short bf16x8;
typedef __attribute__((ext_vector_type(4))) float f32x4;

static __device__ __forceinline__ unsigned short f2bf(float f) {
    unsigned u = __builtin_bit_cast(unsigned, f);
    unsigned r = (u + 0x7fffu + ((u >> 16) & 1u)) >> 16;   // RN-even
    return (unsigned short)r;
}
static __device__ __forceinline__ float bf2f(unsigned short h) {
    unsigned u = ((unsigned)h) << 16;
    return __builtin_bit_cast(float, u);
}

// ---------------- CSR build ----------------
// histogram + per-edge rank (rank store is coalesced fire-and-forget)
__global__ __launch_bounds__(256) void k_count(const int* __restrict__ dst, int* __restrict__ cnt,
                                               int* __restrict__ rank) {
    int e = blockIdx.x * 256 + threadIdx.x;
    if (e < NE) rank[e] = atomicAdd(&cnt[dst[e]], 1);
}

__global__ __launch_bounds__(256) void k_scan_partial(const int* __restrict__ cnt, int* __restrict__ blockSums) {
    __shared__ int s[256];
    int t = threadIdx.x;
    int i = blockIdx.x * 256 + t;
    s[t] = (i < NN) ? cnt[i] : 0;
    __syncthreads();
    for (int off = 128; off > 0; off >>= 1) {
        if (t < off) s[t] += s[t + off];
        __syncthreads();
    }
    if (t == 0) blockSums[blockIdx.x] = s[0];
}

__global__ __launch_bounds__(256) void k_scan_blocks(int* __restrict__ blockSums, int* __restrict__ row_ptr) {
    __shared__ int s[256];
    int t = threadIdx.x;
    int v = (t < NBLK) ? blockSums[t] : 0;
    s[t] = v;
    __syncthreads();
    for (int off = 1; off < 256; off <<= 1) {
        int y = (t >= off) ? s[t - off] : 0;
        __syncthreads();
        s[t] += y;
        __syncthreads();
    }
    if (t < NBLK) blockSums[t] = s[t] - v;  // exclusive block offsets
    if (t == 0) row_ptr[NN] = NE;
}

// exclusive scan -> row_ptr; also dinv = rsqrt(deg+1)
__global__ __launch_bounds__(256) void k_scan_final(const int* __restrict__ cnt, const int* __restrict__ blockOffs,
                                                    int* __restrict__ row_ptr, float* __restrict__ dinv) {
    __shared__ int s[256];
    int t = threadIdx.x;
    int i = blockIdx.x * 256 + t;
    int v = (i < NN) ? cnt[i] : 0;
    s[t] = v;
    __syncthreads();
    for (int off = 1; off < 256; off <<= 1) {
        int y = (t >= off) ? s[t - off] : 0;
        __syncthreads();
        s[t] += y;
        __syncthreads();
    }
    if (i < NN) {
        row_ptr[i] = s[t] - v + blockOffs[blockIdx.x];
        dinv[i] = rsqrtf((float)v + 1.0f);
    }
}

// no atomics: pos = row_ptr[dst] + rank
__global__ __launch_bounds__(256) void k_fill(const int* __restrict__ src, const int* __restrict__ dst,
                                              const int* __restrict__ rank, const int* __restrict__ row_ptr,
                                              unsigned short* __restrict__ csr) {
    int e = blockIdx.x * 256 + threadIdx.x;
    if (e < NE) {
        int d = dst[e];
        csr[row_ptr[d] + rank[e]] = (unsigned short)src[e];
    }
}

// ---------------- W prep: fp32 [k][n] -> swizzled bf16 hi/lo images of W^T [n][k] ----------------
__global__ __launch_bounds__(256) void k_prepw(const float* __restrict__ W1, const float* __restrict__ W2,
                                               char* __restrict__ img1, char* __restrict__ img2) {
    int b = blockIdx.x;
    const float* W = (b < 64) ? W1 : W2;
    char* img = (b < 64) ? img1 : img2;
    int e = (b & 63) * 256 + threadIdx.x;  // 0..16383
    int k = e >> 7, n = e & 127;
    float f = W[e];
    unsigned short hi = f2bf(f);
    float rem = f - bf2f(hi);
    unsigned short lo = f2bf(rem);
    unsigned off = (unsigned)((n << 8) + (k << 1)) ^ (unsigned)((n & 7) << 4);
    *(unsigned short*)(img + off) = hi;
    *(unsigned short*)(img + 32768 + off) = lo;
}

// ---------------- MFMA GEMM: H = act(A) @ W, bf16x3 split, output = fp16 quarter-table [4][NN][32] ----------------
// A_FP16: A is a quarter-table fp16; else fp32 linear [NN][128].
template <bool RELU_IN, bool A_FP16>
__global__ __launch_bounds__(256) void k_mgemm(const void* __restrict__ Av, const char* __restrict__ wimg,
                                               __half* __restrict__ H) {
    __shared__ char lds[65536];
    const int t = threadIdx.x;

    {   // stage both swizzled bf16 images (byte-identical copy)
        const float4* gv = (const float4*)wimg;
        float4* lv = (float4*)lds;
#pragma unroll
        for (int i = 0; i < 16; ++i) lv[i * 256 + t] = gv[i * 256 + t];
    }
    __syncthreads();

    const int lane = t & 63;
    const int wv = t >> 6;
    const int r0 = blockIdx.x * 64 + wv * 16;
    const int rl = lane & 15;              // A row in strip / C col
    const int g = lane >> 4;               // k-group 0..3
    int arow = r0 + rl;
    if (arow >= NN) arow = NN - 1;

    f32x4 acc[8];
#pragma unroll
    for (int j = 0; j < 8; ++j) acc[j] = (f32x4){0.f, 0.f, 0.f, 0.f};

#pragma unroll
    for (int ks = 0; ks < 4; ++ks) {
        float av[8];
        if (A_FP16) {
            const __half* A = (const __half*)Av;
            const __half* ap = A + (size_t)ks * (NN * 32) + (size_t)arow * 32 + g * 8;
            float4 raw = *(const float4*)ap;   // 8 halves
            const __half2* hh = (const __half2*)&raw;
            float2 t0 = __half22float2(hh[0]);
            float2 t1 = __half22float2(hh[1]);
            float2 t2 = __half22float2(hh[2]);
            float2 t3 = __half22float2(hh[3]);
            av[0] = t0.x; av[1] = t0.y; av[2] = t1.x; av[3] = t1.y;
            av[4] = t2.x; av[5] = t2.y; av[6] = t3.x; av[7] = t3.y;
        } else {
            const float* A = (const float*)Av;
            const float* ar = A + (size_t)arow * D + g * 8 + ks * 32;
            float4 p0 = *(const float4*)ar;
            float4 p1 = *(const float4*)(ar + 4);
            av[0] = p0.x; av[1] = p0.y; av[2] = p0.z; av[3] = p0.w;
            av[4] = p1.x; av[5] = p1.y; av[6] = p1.z; av[7] = p1.w;
        }
        bf16x8 ah, al;
#pragma unroll
        for (int i = 0; i < 8; ++i) {
            float a = RELU_IN ? fmaxf(av[i], 0.f) : av[i];
            unsigned short h = f2bf(a);
            ah[i] = (short)h;
            al[i] = (short)f2bf(a - bf2f(h));
        }
        const int kofs = (ks * 32 + g * 8) << 1;
#pragma unroll
        for (int j = 0; j < 8; ++j) {
            int n = j * 16 + rl;
            unsigned off = (unsigned)((n << 8) + kofs) ^ (unsigned)((n & 7) << 4);
            bf16x8 bh = *(const bf16x8*)(lds + off);
            bf16x8 bl = *(const bf16x8*)(lds + 32768 + off);
            acc[j] = __builtin_amdgcn_mfma_f32_16x16x32_bf16(ah, bh, acc[j], 0, 0, 0);
            acc[j] = __builtin_amdgcn_mfma_f32_16x16x32_bf16(ah, bl, acc[j], 0, 0, 0);
            acc[j] = __builtin_amdgcn_mfma_f32_16x16x32_bf16(al, bh, acc[j], 0, 0, 0);
        }
    }

    // C/D: col = lane&15 (+16j), row = (lane>>4)*4 + reg; store into quarter-table
#pragma unroll
    for (int j = 0; j < 8; ++j) {
        const int qq = j >> 1;                      // quarter = col>>5
        const int cq = (j & 1) * 16 + rl;           // col within quarter
#pragma unroll
        for (int i = 0; i < 4; ++i) {
            int row = r0 + g * 4 + i;
            if (row < NN) H[(size_t)qq * (NN * 32) + (size_t)row * 32 + cq] = __float2half(acc[j][i]);
        }
    }
}

// ---------------- pull aggregation: one wave per (node, quarter); 4 lanes per edge-row ----------------
// lane = g*4 + rl; group g in 0..15 handles edges beg+g, beg+g+16, ...; lane's dims = rl*8..rl*8+7 of quarter
template <bool OUT_FP16>
__global__ __launch_bounds__(256) void k_pull(const __half* __restrict__ H, const float* __restrict__ dinv,
                                              const float* __restrict__ b, const int* __restrict__ row_ptr,
                                              const unsigned short* __restrict__ csr, void* __restrict__ outv) {
    int wid = (blockIdx.x * 256 + threadIdx.x) >> 6;      // 0 .. NN*4-1
    int lane = threadIdx.x & 63;
    int node = __builtin_amdgcn_readfirstlane(wid >> 2);
    int q = __builtin_amdgcn_readfirstlane(wid & 3);
    int rl = lane & 3;      // dim octet within quarter
    int g = lane >> 2;      // edge group 0..15

    const __half* Hq = H + (size_t)q * (NN * 32);
    float dd = dinv[node];  // wave-uniform

    float2 a0 = {0.f, 0.f}, a1 = {0.f, 0.f}, a2 = {0.f, 0.f}, a3 = {0.f, 0.f};

    int beg = row_ptr[node];
    int end = row_ptr[node + 1];
    for (int i = beg + g; i < end; i += 16) {
        int s = csr[i];                       // broadcast within 4-lane group
        float c = dinv[s] * dd;               // exact coef, L2-hot gather
        float4 raw = *(const float4*)(Hq + (size_t)s * 32 + rl * 8);  // 8 halves, 16B
        const __half2* hh = (const __half2*)&raw;
        float2 f0 = __half22float2(hh[0]);
        float2 f1 = __half22float2(hh[1]);
        float2 f2 = __half22float2(hh[2]);
        float2 f3 = __half22float2(hh[3]);
        a0.x = fmaf(f0.x, c, a0.x); a0.y = fmaf(f0.y, c, a0.y);
        a1.x = fmaf(f1.x, c, a1.x); a1.y = fmaf(f1.y, c, a1.y);
        a2.x = fmaf(f2.x, c, a2.x); a2.y = fmaf(f2.y, c, a2.y);
        a3.x = fmaf(f3.x, c, a3.x); a3.y = fmaf(f3.y, c, a3.y);
    }

    // butterfly-reduce the 16 lane-groups (xor 4,8,16,32)
    float v[8] = {a0.x, a0.y, a1.x, a1.y, a2.x, a2.y, a3.x, a3.y};
#pragma unroll
    for (int i = 0; i < 8; ++i) {
        v[i] += __shfl_xor(v[i], 4);
        v[i] += __shfl_xor(v[i], 8);
        v[i] += __shfl_xor(v[i], 16);
        v[i] += __shfl_xor(v[i], 32);
    }

    if (g == 0) {   // lanes 0..3 hold the full sums; add self-loop + bias, store
        float s2 = dd * dd;
        float4 raw = *(const float4*)(Hq + (size_t)node * 32 + rl * 8);
        const __half2* hh = (const __half2*)&raw;
        float2 s0 = __half22float2(hh[0]);
        float2 s1 = __half22float2(hh[1]);
        float2 s2v = __half22float2(hh[2]);
        float2 s3 = __half22float2(hh[3]);
        const float* bq = b + q * 32 + rl * 8;
        float4 b0 = *(const float4*)bq;
        float4 b1v = *(const float4*)(bq + 4);
        float r[8];
        r[0] = fmaf(s0.x, s2, v[0] + b0.x);
        r[1] = fmaf(s0.y, s2, v[1] + b0.y);
        r[2] = fmaf(s1.x, s2, v[2] + b0.z);
        r[3] = fmaf(s1.y, s2, v[3] + b0.w);
        r[4] = fmaf(s2v.x, s2, v[4] + b1v.x);
        r[5] = fmaf(s2v.y, s2, v[5] + b1v.y);
        r[6] = fmaf(s3.x, s2, v[6] + b1v.z);
        r[7] = fmaf(s3.y, s2, v[7] + b1v.w);
        if (OUT_FP16) {
            __half* out = (__half*)outv;                    // quarter-table layout
            __half2 o[4];
            o[0] = __floats2half2_rn(r[0], r[1]);
            o[1] = __floats2half2_rn(r[2], r[3]);
            o[2] = __floats2half2_rn(r[4], r[5]);
            o[3] = __floats2half2_rn(r[6], r[7]);
            *(float4*)(out + (size_t)q * (NN * 32) + (size_t)node * 32 + rl * 8) = *(float4*)o;
        } else {
            float* out = (float*)outv;                      // linear [NN][128]
            float* op = out + (size_t)node * D + q * 32 + rl * 8;
            *(float4*)op = make_float4(r[0], r[1], r[2], r[3]);
            *(float4*)(op + 4) = make_float4(r[4], r[5], r[6], r[7]);
        }
    }
}

extern "C" void kernel_launch(void* const* d_in, const int* in_sizes, int n_in,
                              void* d_out, int out_size, void* d_ws, size_t ws_size,
                              hipStream_t stream) {
    const float* x  = (const float*)d_in[0];
    const int*   ei = (const int*)d_in[1];
    const float* W1 = (const float*)d_in[2];
    const float* b1 = (const float*)d_in[3];
    const float* W2 = (const float*)d_in[4];
    const float* b2 = (const float*)d_in[5];
    float* out = (float*)d_out;

    const int* src = ei;
    const int* dst = ei + NE;

    char* ws = (char*)d_ws;
    int*    cnt       = (int*)   (ws + 0);         // 200000 B
    int*    row_ptr   = (int*)   (ws + 204800);    // NN+1 ints
    int*    blockSums = (int*)   (ws + 409600);    // 784 B
    float*  dinv      = (float*) (ws + 410624);    // 200000 B
    char*   wimg1     = (char*)  (ws + 614400);    // 64 KB
    char*   wimg2     = (char*)  (ws + 679936);    // 64 KB
    int*    rank      = (int*)   (ws + 745472);    // NE ints = 3.2 MB
    unsigned short* csr = (unsigned short*)(ws + 3945472);  // NE u16 = 1.6 MB
    __half* h         = (__half*)(ws + 5545472);   // [4][NN][32] fp16 = 12.8 MB
    __half* h2        = (__half*)(ws + 18345472);  // [4][NN][32] fp16 = 12.8 MB

    const int nBlkEdge = (NE + 255) / 256;   // 3125
    const int nBlkGemm = (NN + 63) / 64;     // 782
    const int nBlkPull = NN;                 // one wave per (node,quarter), 4 waves/block

    // CSR build + norm + weight prep
    hipMemsetAsync(cnt, 0, (size_t)NN * 4, stream);
    k_count<<<nBlkEdge, 256, 0, stream>>>(dst, cnt, rank);
    k_scan_partial<<<NBLK, 256, 0, stream>>>(cnt, blockSums);
    k_scan_blocks<<<1, 256, 0, stream>>>(blockSums, row_ptr);
    k_scan_final<<<NBLK, 256, 0, stream>>>(cnt, blockSums, row_ptr, dinv);
    k_fill<<<nBlkEdge, 256, 0, stream>>>(src, dst, rank, row_ptr, csr);
    k_prepw<<<128, 256, 0, stream>>>(W1, W2, wimg1, wimg2);

    // layer 1: gemm (x fp32 -> h quarter-table fp16), pull (h -> h2 fp16, +b1)
    k_mgemm<false, false><<<nBlkGemm, 256, 0, stream>>>(x, wimg1, h);
    k_pull<true><<<nBlkPull, 256, 0, stream>>>(h, dinv, b1, row_ptr, csr, h2);

    // layer 2: gemm (relu(h2) fp16 -> h), pull (h -> out fp32, +b2)
    k_mgemm<true, true><<<nBlkGemm, 256, 0, stream>>>(h2, wimg2, h);
    k_pull<false><<<nBlkPull, 256, 0, stream>>>(h, dinv, b2, row_ptr, csr, out);
}

// Round 8
// 234.144 us; speedup vs baseline: 1.3475x; 1.3475x over previous
//
#include <hip/hip_runtime.h>
#include <hip/hip_fp16.h>

#define NN 50000
#define NE 800000
#define D 128
#define NBLK ((NN + 255) / 256)   // 196 blocks over nodes

typedef __attribute__((ext_vector_type(8))) _Float16 f16x8;
typedef __attribute__((ext_vector_type(8))) short short8;
typedef __attribute__((ext_vector_type(4))) float f32x4;

// ---------------- CSR build ----------------
// histogram + per-edge rank (rank store is coalesced fire-and-forget)
__global__ __launch_bounds__(256) void k_count(const int* __restrict__ dst, int* __restrict__ cnt,
                                               int* __restrict__ rank) {
    int e = blockIdx.x * 256 + threadIdx.x;
    if (e < NE) rank[e] = atomicAdd(&cnt[dst[e]], 1);
}

__global__ __launch_bounds__(256) void k_scan_partial(const int* __restrict__ cnt, int* __restrict__ blockSums) {
    __shared__ int s[256];
    int t = threadIdx.x;
    int i = blockIdx.x * 256 + t;
    s[t] = (i < NN) ? cnt[i] : 0;
    __syncthreads();
    for (int off = 128; off > 0; off >>= 1) {
        if (t < off) s[t] += s[t + off];
        __syncthreads();
    }
    if (t == 0) blockSums[blockIdx.x] = s[0];
}

__global__ __launch_bounds__(256) void k_scan_blocks(int* __restrict__ blockSums, int* __restrict__ row_ptr) {
    __shared__ int s[256];
    int t = threadIdx.x;
    int v = (t < NBLK) ? blockSums[t] : 0;
    s[t] = v;
    __syncthreads();
    for (int off = 1; off < 256; off <<= 1) {
        int y = (t >= off) ? s[t - off] : 0;
        __syncthreads();
        s[t] += y;
        __syncthreads();
    }
    if (t < NBLK) blockSums[t] = s[t] - v;  // exclusive block offsets
    if (t == 0) row_ptr[NN] = NE;
}

// exclusive scan -> row_ptr; also dinv = rsqrt(deg+1)
__global__ __launch_bounds__(256) void k_scan_final(const int* __restrict__ cnt, const int* __restrict__ blockOffs,
                                                    int* __restrict__ row_ptr, float* __restrict__ dinv) {
    __shared__ int s[256];
    int t = threadIdx.x;
    int i = blockIdx.x * 256 + t;
    int v = (i < NN) ? cnt[i] : 0;
    s[t] = v;
    __syncthreads();
    for (int off = 1; off < 256; off <<= 1) {
        int y = (t >= off) ? s[t - off] : 0;
        __syncthreads();
        s[t] += y;
        __syncthreads();
    }
    if (i < NN) {
        row_ptr[i] = s[t] - v + blockOffs[blockIdx.x];
        dinv[i] = rsqrtf((float)v + 1.0f);
    }
}

// no atomics: pos = row_ptr[dst] + rank
__global__ __launch_bounds__(256) void k_fill(const int* __restrict__ src, const int* __restrict__ dst,
                                              const int* __restrict__ rank, const int* __restrict__ row_ptr,
                                              unsigned short* __restrict__ csr) {
    int e = blockIdx.x * 256 + threadIdx.x;
    if (e < NE) {
        int d = dst[e];
        csr[row_ptr[d] + rank[e]] = (unsigned short)src[e];
    }
}

// ---------------- W prep: fp32 [k][n] -> swizzled fp16 hi/lo images of W^T [n][k] ----------------
// image: 32768 B hi, then 32768 B lo. byte offset of (n,k): (n*256 + k*2) ^ ((n&7)<<4)
__global__ __launch_bounds__(256) void k_prepw(const float* __restrict__ W1, const float* __restrict__ W2,
                                               char* __restrict__ img1, char* __restrict__ img2) {
    int b = blockIdx.x;
    const float* W = (b < 64) ? W1 : W2;
    char* img = (b < 64) ? img1 : img2;
    int e = (b & 63) * 256 + threadIdx.x;  // 0..16383
    int k = e >> 7, n = e & 127;
    float f = W[e];
    __half hi = __float2half_rn(f);
    float rem = f - __half2float(hi);
    __half lo = __float2half_rn(rem);
    unsigned off = (unsigned)((n << 8) + (k << 1)) ^ (unsigned)((n & 7) << 4);
    *(__half*)(img + off) = hi;
    *(__half*)(img + 32768 + off) = lo;
}

// ---------------- MFMA GEMM: H[M,128] = act(A[M,128]) @ W[128,128], fp16 A, W=hi+lo fp16, fp16 out ----------------
// A_FP16: A is fp16 linear [NN][128]; else fp32 linear [NN][128].
template <bool RELU_IN, bool A_FP16>
__global__ __launch_bounds__(256) void k_mgemm(const void* __restrict__ Av, const char* __restrict__ wimg,
                                               __half* __restrict__ H) {
    __shared__ char lds[65536];
    const int t = threadIdx.x;

    {   // stage both swizzled fp16 images (byte-identical copy)
        const float4* gv = (const float4*)wimg;
        float4* lv = (float4*)lds;
#pragma unroll
        for (int i = 0; i < 16; ++i) lv[i * 256 + t] = gv[i * 256 + t];
    }
    __syncthreads();

    const int lane = t & 63;
    const int wv = t >> 6;
    const int r0 = blockIdx.x * 64 + wv * 16;
    const int rl = lane & 15;              // A row in strip / C col
    const int g = lane >> 4;               // k-group 0..3
    int arow = r0 + rl;
    if (arow >= NN) arow = NN - 1;

    f32x4 acc[8];
#pragma unroll
    for (int j = 0; j < 8; ++j) acc[j] = (f32x4){0.f, 0.f, 0.f, 0.f};

#pragma unroll
    for (int ks = 0; ks < 4; ++ks) {
        f16x8 a;
        if (A_FP16) {
            const __half* A = (const __half*)Av;
            float4 raw = *(const float4*)(A + (size_t)arow * D + ks * 32 + g * 8);  // 8 halves
            if (RELU_IN) {
                short8 s = __builtin_bit_cast(short8, raw);
#pragma unroll
                for (int i = 0; i < 8; ++i) s[i] = (s[i] & (short)0x8000) ? (short)0 : s[i];
                a = __builtin_bit_cast(f16x8, s);
            } else {
                a = __builtin_bit_cast(f16x8, raw);
            }
        } else {
            const float* A = (const float*)Av;
            const float* ar = A + (size_t)arow * D + ks * 32 + g * 8;
            float4 p0 = *(const float4*)ar;
            float4 p1 = *(const float4*)(ar + 4);
            float av8[8] = {p0.x, p0.y, p0.z, p0.w, p1.x, p1.y, p1.z, p1.w};
#pragma unroll
            for (int i = 0; i < 8; ++i) {
                float f = RELU_IN ? fmaxf(av8[i], 0.f) : av8[i];
                a[i] = (_Float16)f;
            }
        }
        const int kofs = (ks * 32 + g * 8) << 1;   // byte offset of k within row
#pragma unroll
        for (int j = 0; j < 8; ++j) {
            int n = j * 16 + rl;
            unsigned off = (unsigned)((n << 8) + kofs) ^ (unsigned)((n & 7) << 4);
            f16x8 bh = *(const f16x8*)(lds + off);
            f16x8 bl = *(const f16x8*)(lds + 32768 + off);
            acc[j] = __builtin_amdgcn_mfma_f32_16x16x32_f16(a, bh, acc[j], 0, 0, 0);
            acc[j] = __builtin_amdgcn_mfma_f32_16x16x32_f16(a, bl, acc[j], 0, 0, 0);
        }
    }

    // C/D: col = lane&15 (+16j), row = (lane>>4)*4 + reg
#pragma unroll
    for (int j = 0; j < 8; ++j) {
#pragma unroll
        for (int i = 0; i < 4; ++i) {
            int row = r0 + g * 4 + i;
            if (row < NN) H[(size_t)row * D + j * 16 + rl] = __float2half(acc[j][i]);
        }
    }
}

// ---------------- pull aggregation: one wave per node, 16 lanes per edge-row, 2-deep unroll ----------------
template <bool OUT_FP16>
__global__ __launch_bounds__(256) void k_pull(const __half* __restrict__ H, const float* __restrict__ dinv,
                                              const float* __restrict__ b, const int* __restrict__ row_ptr,
                                              const unsigned short* __restrict__ csr, void* __restrict__ outv) {
    int wid = (blockIdx.x * 256 + threadIdx.x) >> 6;
    int lane = threadIdx.x & 63;
    int node = __builtin_amdgcn_readfirstlane(wid);  // wave-uniform
    int rl = lane & 15;
    int g = lane >> 4;

    float dd = dinv[node];   // wave-uniform scalar

    float2 a0 = {0.f, 0.f}, a1 = {0.f, 0.f}, a2 = {0.f, 0.f}, a3 = {0.f, 0.f};
    float2 c0b = {0.f, 0.f}, c1b = {0.f, 0.f}, c2b = {0.f, 0.f}, c3b = {0.f, 0.f};

    int beg = row_ptr[node];
    int end = row_ptr[node + 1];
    for (int i = beg + g; i < end; i += 8) {
        int i1 = i + 4;
        bool ok = i1 < end;
        int s0 = csr[i];
        int s1 = csr[ok ? i1 : i];
        float c0 = dinv[s0] * dd;
        float c1 = ok ? dinv[s1] * dd : 0.f;
        float4 raw0 = *(const float4*)(H + (size_t)s0 * D + rl * 8);
        float4 raw1 = *(const float4*)(H + (size_t)s1 * D + rl * 8);
        const __half2* h0 = (const __half2*)&raw0;
        const __half2* h1 = (const __half2*)&raw1;
        float2 f0 = __half22float2(h0[0]);
        float2 f1 = __half22float2(h0[1]);
        float2 f2 = __half22float2(h0[2]);
        float2 f3 = __half22float2(h0[3]);
        a0.x = fmaf(f0.x, c0, a0.x); a0.y = fmaf(f0.y, c0, a0.y);
        a1.x = fmaf(f1.x, c0, a1.x); a1.y = fmaf(f1.y, c0, a1.y);
        a2.x = fmaf(f2.x, c0, a2.x); a2.y = fmaf(f2.y, c0, a2.y);
        a3.x = fmaf(f3.x, c0, a3.x); a3.y = fmaf(f3.y, c0, a3.y);
        float2 g0 = __half22float2(h1[0]);
        float2 g1 = __half22float2(h1[1]);
        float2 g2 = __half22float2(h1[2]);
        float2 g3 = __half22float2(h1[3]);
        c0b.x = fmaf(g0.x, c1, c0b.x); c0b.y = fmaf(g0.y, c1, c0b.y);
        c1b.x = fmaf(g1.x, c1, c1b.x); c1b.y = fmaf(g1.y, c1, c1b.y);
        c2b.x = fmaf(g2.x, c1, c2b.x); c2b.y = fmaf(g2.y, c1, c2b.y);
        c3b.x = fmaf(g3.x, c1, c3b.x); c3b.y = fmaf(g3.y, c1, c3b.y);
    }
    a0.x += c0b.x; a0.y += c0b.y;
    a1.x += c1b.x; a1.y += c1b.y;
    a2.x += c2b.x; a2.y += c2b.y;
    a3.x += c3b.x; a3.y += c3b.y;

    // butterfly-reduce the 4 lane-groups (xor 16, 32)
    float v[8] = {a0.x, a0.y, a1.x, a1.y, a2.x, a2.y, a3.x, a3.y};
#pragma unroll
    for (int i = 0; i < 8; ++i) {
        v[i] += __shfl_xor(v[i], 16);
        v[i] += __shfl_xor(v[i], 32);
    }

    if (g == 0) {
        float s2 = dd * dd;
        float4 raw = *(const float4*)(H + (size_t)node * D + rl * 8);
        const __half2* hh = (const __half2*)&raw;
        float2 s0 = __half22float2(hh[0]);
        float2 s1 = __half22float2(hh[1]);
        float2 s2v = __half22float2(hh[2]);
        float2 s3 = __half22float2(hh[3]);
        float4 b0 = ((const float4*)b)[rl * 2];
        float4 b1v = ((const float4*)b)[rl * 2 + 1];
        float r[8];
        r[0] = fmaf(s0.x, s2, v[0] + b0.x);
        r[1] = fmaf(s0.y, s2, v[1] + b0.y);
        r[2] = fmaf(s1.x, s2, v[2] + b0.z);
        r[3] = fmaf(s1.y, s2, v[3] + b0.w);
        r[4] = fmaf(s2v.x, s2, v[4] + b1v.x);
        r[5] = fmaf(s2v.y, s2, v[5] + b1v.y);
        r[6] = fmaf(s3.x, s2, v[6] + b1v.z);
        r[7] = fmaf(s3.y, s2, v[7] + b1v.w);
        if (OUT_FP16) {
            __half* out = (__half*)outv;          // fp16 linear [NN][128]
            __half2 o[4];
            o[0] = __floats2half2_rn(r[0], r[1]);
            o[1] = __floats2half2_rn(r[2], r[3]);
            o[2] = __floats2half2_rn(r[4], r[5]);
            o[3] = __floats2half2_rn(r[6], r[7]);
            *(float4*)(out + (size_t)node * D + rl * 8) = *(float4*)o;
        } else {
            float* out = (float*)outv;            // fp32 linear [NN][128]
            float* op = out + (size_t)node * D + rl * 8;
            *(float4*)op = make_float4(r[0], r[1], r[2], r[3]);
            *(float4*)(op + 4) = make_float4(r[4], r[5], r[6], r[7]);
        }
    }
}

extern "C" void kernel_launch(void* const* d_in, const int* in_sizes, int n_in,
                              void* d_out, int out_size, void* d_ws, size_t ws_size,
                              hipStream_t stream) {
    const float* x  = (const float*)d_in[0];
    const int*   ei = (const int*)d_in[1];
    const float* W1 = (const float*)d_in[2];
    const float* b1 = (const float*)d_in[3];
    const float* W2 = (const float*)d_in[4];
    const float* b2 = (const float*)d_in[5];
    float* out = (float*)d_out;

    const int* src = ei;
    const int* dst = ei + NE;

    char* ws = (char*)d_ws;
    int*    cnt       = (int*)   (ws + 0);         // 200000 B
    int*    row_ptr   = (int*)   (ws + 204800);    // NN+1 ints
    int*    blockSums = (int*)   (ws + 409600);    // 784 B
    float*  dinv      = (float*) (ws + 410624);    // 200000 B
    char*   wimg1     = (char*)  (ws + 614400);    // 64 KB (fp16 hi+lo, swizzled)
    char*   wimg2     = (char*)  (ws + 679936);    // 64 KB
    int*    rank      = (int*)   (ws + 745472);    // NE ints = 3.2 MB
    unsigned short* csr = (unsigned short*)(ws + 3945472);  // NE u16 = 1.6 MB
    __half* h         = (__half*)(ws + 5545472);   // [NN][128] fp16 = 12.8 MB
    __half* h2        = (__half*)(ws + 18345472);  // [NN][128] fp16 = 12.8 MB

    const int nBlkEdge = (NE + 255) / 256;   // 3125
    const int nBlkGemm = (NN + 63) / 64;     // 782
    const int nBlkPull = NN / 4;             // 12500 (4 waves/block, 1 wave/node)

    // CSR build + norm + weight prep
    hipMemsetAsync(cnt, 0, (size_t)NN * 4, stream);
    k_count<<<nBlkEdge, 256, 0, stream>>>(dst, cnt, rank);
    k_scan_partial<<<NBLK, 256, 0, stream>>>(cnt, blockSums);
    k_scan_blocks<<<1, 256, 0, stream>>>(blockSums, row_ptr);
    k_scan_final<<<NBLK, 256, 0, stream>>>(cnt, blockSums, row_ptr, dinv);
    k_fill<<<nBlkEdge, 256, 0, stream>>>(src, dst, rank, row_ptr, csr);
    k_prepw<<<128, 256, 0, stream>>>(W1, W2, wimg1, wimg2);

    // layer 1: gemm (x fp32 -> h fp16), pull (h -> h2 fp16, +b1)
    k_mgemm<false, false><<<nBlkGemm, 256, 0, stream>>>(x, wimg1, h);
    k_pull<true><<<nBlkPull, 256, 0, stream>>>(h, dinv, b1, row_ptr, csr, h2);

    // layer 2: gemm (relu(h2) fp16 -> h), pull (h -> out fp32, +b2)
    k_mgemm<true, true><<<nBlkGemm, 256, 0, stream>>>(h2, wimg2, h);
    k_pull<false><<<nBlkPull, 256, 0, stream>>>(h, dinv, b2, row_ptr, csr, out);
}

// Round 9
// 227.457 us; speedup vs baseline: 1.3872x; 1.0294x over previous
//
#include <hip/hip_runtime.h>
#include <hip/hip_fp16.h>

#define NN 50000
#define NE 800000
#define D 128
#define NBLK ((NN + 255) / 256)   // 196 blocks over nodes
#define NBLK_GEMM ((NN + 63) / 64) // 782

typedef __attribute__((ext_vector_type(8))) _Float16 f16x8;
typedef __attribute__((ext_vector_type(8))) short short8;
typedef __attribute__((ext_vector_type(4))) float f32x4;

// ---------------- init: zero cnt (blocks 0..195) + W prep (blocks 196..323) ----------------
// W prep: fp32 [k][n] -> swizzled fp16 hi/lo images of W^T [n][k]
// image: 32768 B hi, then 32768 B lo. byte offset of (n,k): (n*256 + k*2) ^ ((n&7)<<4)
__global__ __launch_bounds__(256) void k_init(int* __restrict__ cnt,
                                              const float* __restrict__ W1, const float* __restrict__ W2,
                                              char* __restrict__ img1, char* __restrict__ img2) {
    int b = blockIdx.x;
    if (b < NBLK) {
        int i = b * 256 + threadIdx.x;
        if (i < NN) cnt[i] = 0;
    } else {
        int pb = b - NBLK;  // 0..127
        const float* W = (pb < 64) ? W1 : W2;
        char* img = (pb < 64) ? img1 : img2;
        int e = (pb & 63) * 256 + threadIdx.x;  // 0..16383
        int k = e >> 7, n = e & 127;
        float f = W[e];
        __half hi = __float2half_rn(f);
        float rem = f - __half2float(hi);
        __half lo = __float2half_rn(rem);
        unsigned off = (unsigned)((n << 8) + (k << 1)) ^ (unsigned)((n & 7) << 4);
        *(__half*)(img + off) = hi;
        *(__half*)(img + 32768 + off) = lo;
    }
}

// ---------------- histogram + per-edge rank ----------------
__global__ __launch_bounds__(256) void k_count(const int* __restrict__ dst, int* __restrict__ cnt,
                                               unsigned short* __restrict__ rank) {
    int e = blockIdx.x * 256 + threadIdx.x;
    if (e < NE) rank[e] = (unsigned short)atomicAdd(&cnt[dst[e]], 1);
}

__global__ __launch_bounds__(256) void k_scan_partial(const int* __restrict__ cnt, int* __restrict__ blockSums) {
    __shared__ int s[256];
    int t = threadIdx.x;
    int i = blockIdx.x * 256 + t;
    s[t] = (i < NN) ? cnt[i] : 0;
    __syncthreads();
    for (int off = 128; off > 0; off >>= 1) {
        if (t < off) s[t] += s[t + off];
        __syncthreads();
    }
    if (t == 0) blockSums[blockIdx.x] = s[0];
}

// block offset computed in-kernel from blockSums; exclusive scan -> row_ptr; dinv = rsqrt(deg+1)
__global__ __launch_bounds__(256) void k_scan_final(const int* __restrict__ cnt, const int* __restrict__ blockSums,
                                                    int* __restrict__ row_ptr, float* __restrict__ dinv) {
    __shared__ int s[256];
    int t = threadIdx.x;

    // sum blockSums[0..blockIdx.x)
    s[t] = (t < NBLK && t < (int)blockIdx.x) ? blockSums[t] : 0;
    __syncthreads();
    for (int off = 128; off > 0; off >>= 1) {
        if (t < off) s[t] += s[t + off];
        __syncthreads();
    }
    int blockOff = s[0];
    __syncthreads();

    int i = blockIdx.x * 256 + t;
    int v = (i < NN) ? cnt[i] : 0;
    s[t] = v;
    __syncthreads();
    for (int off = 1; off < 256; off <<= 1) {
        int y = (t >= off) ? s[t - off] : 0;
        __syncthreads();
        s[t] += y;
        __syncthreads();
    }
    if (i < NN) {
        row_ptr[i] = s[t] - v + blockOff;
        dinv[i] = rsqrtf((float)v + 1.0f);
    }
    if (blockIdx.x == 0 && t == 0) row_ptr[NN] = NE;
}

// ---------------- GEMM core: H[M,128] = act(A[M,128]) @ W[128,128], fp16 A, W=hi+lo fp16, fp16 out ----------------
template <bool RELU_IN, bool A_FP16>
static __device__ __forceinline__ void gemm_core(char* lds, const void* __restrict__ Av,
                                                 const char* __restrict__ wimg, __half* __restrict__ H,
                                                 int bid, int t) {
    {   // stage both swizzled fp16 images (byte-identical copy)
        const float4* gv = (const float4*)wimg;
        float4* lv = (float4*)lds;
#pragma unroll
        for (int i = 0; i < 16; ++i) lv[i * 256 + t] = gv[i * 256 + t];
    }
    __syncthreads();

    const int lane = t & 63;
    const int wv = t >> 6;
    const int r0 = bid * 64 + wv * 16;
    const int rl = lane & 15;              // A row in strip / C col
    const int g = lane >> 4;               // k-group 0..3
    int arow = r0 + rl;
    if (arow >= NN) arow = NN - 1;

    f32x4 acc[8];
#pragma unroll
    for (int j = 0; j < 8; ++j) acc[j] = (f32x4){0.f, 0.f, 0.f, 0.f};

#pragma unroll
    for (int ks = 0; ks < 4; ++ks) {
        f16x8 a;
        if (A_FP16) {
            const __half* A = (const __half*)Av;
            float4 raw = *(const float4*)(A + (size_t)arow * D + ks * 32 + g * 8);  // 8 halves
            if (RELU_IN) {
                short8 s = __builtin_bit_cast(short8, raw);
#pragma unroll
                for (int i = 0; i < 8; ++i) s[i] = (s[i] & (short)0x8000) ? (short)0 : s[i];
                a = __builtin_bit_cast(f16x8, s);
            } else {
                a = __builtin_bit_cast(f16x8, raw);
            }
        } else {
            const float* A = (const float*)Av;
            const float* ar = A + (size_t)arow * D + ks * 32 + g * 8;
            float4 p0 = *(const float4*)ar;
            float4 p1 = *(const float4*)(ar + 4);
            float av8[8] = {p0.x, p0.y, p0.z, p0.w, p1.x, p1.y, p1.z, p1.w};
#pragma unroll
            for (int i = 0; i < 8; ++i) {
                float f = RELU_IN ? fmaxf(av8[i], 0.f) : av8[i];
                a[i] = (_Float16)f;
            }
        }
        const int kofs = (ks * 32 + g * 8) << 1;   // byte offset of k within row
#pragma unroll
        for (int j = 0; j < 8; ++j) {
            int n = j * 16 + rl;
            unsigned off = (unsigned)((n << 8) + kofs) ^ (unsigned)((n & 7) << 4);
            f16x8 bh = *(const f16x8*)(lds + off);
            f16x8 bl = *(const f16x8*)(lds + 32768 + off);
            acc[j] = __builtin_amdgcn_mfma_f32_16x16x32_f16(a, bh, acc[j], 0, 0, 0);
            acc[j] = __builtin_amdgcn_mfma_f32_16x16x32_f16(a, bl, acc[j], 0, 0, 0);
        }
    }

    // C/D: col = lane&15 (+16j), row = (lane>>4)*4 + reg
#pragma unroll
    for (int j = 0; j < 8; ++j) {
#pragma unroll
        for (int i = 0; i < 4; ++i) {
            int row = r0 + g * 4 + i;
            if (row < NN) H[(size_t)row * D + j * 16 + rl] = __float2half(acc[j][i]);
        }
    }
}

// ---------------- fused: gemm-1 (blocks 0..781) + CSR fill (blocks 782..) ----------------
__global__ __launch_bounds__(256) void k_fill_gemm1(const int* __restrict__ src, const int* __restrict__ dst,
                                                    const unsigned short* __restrict__ rank,
                                                    const int* __restrict__ row_ptr,
                                                    unsigned short* __restrict__ csr,
                                                    const float* __restrict__ x, const char* __restrict__ wimg,
                                                    __half* __restrict__ H) {
    __shared__ char lds[65536];
    int bid = blockIdx.x;
    if (bid < NBLK_GEMM) {
        gemm_core<false, false>(lds, x, wimg, H, bid, threadIdx.x);
    } else {
        int e = (bid - NBLK_GEMM) * 256 + threadIdx.x;
        if (e < NE) {
            int d = dst[e];
            csr[row_ptr[d] + rank[e]] = (unsigned short)src[e];
        }
    }
}

// standalone gemm for layer 2
template <bool RELU_IN, bool A_FP16>
__global__ __launch_bounds__(256) void k_mgemm(const void* __restrict__ Av, const char* __restrict__ wimg,
                                               __half* __restrict__ H) {
    __shared__ char lds[65536];
    gemm_core<RELU_IN, A_FP16>(lds, Av, wimg, H, blockIdx.x, threadIdx.x);
}

// ---------------- pull aggregation: one wave per node, 16 lanes per edge-row, 2-deep unroll ----------------
template <bool OUT_FP16>
__global__ __launch_bounds__(256) void k_pull(const __half* __restrict__ H, const float* __restrict__ dinv,
                                              const float* __restrict__ b, const int* __restrict__ row_ptr,
                                              const unsigned short* __restrict__ csr, void* __restrict__ outv) {
    int wid = (blockIdx.x * 256 + threadIdx.x) >> 6;
    int lane = threadIdx.x & 63;
    int node = __builtin_amdgcn_readfirstlane(wid);  // wave-uniform
    int rl = lane & 15;
    int g = lane >> 4;

    float dd = dinv[node];   // wave-uniform scalar

    float2 a0 = {0.f, 0.f}, a1 = {0.f, 0.f}, a2 = {0.f, 0.f}, a3 = {0.f, 0.f};
    float2 c0b = {0.f, 0.f}, c1b = {0.f, 0.f}, c2b = {0.f, 0.f}, c3b = {0.f, 0.f};

    int beg = row_ptr[node];
    int end = row_ptr[node + 1];
    for (int i = beg + g; i < end; i += 8) {
        int i1 = i + 4;
        bool ok = i1 < end;
        int s0 = csr[i];
        int s1 = csr[ok ? i1 : i];
        float c0 = dinv[s0] * dd;
        float c1 = ok ? dinv[s1] * dd : 0.f;
        float4 raw0 = *(const float4*)(H + (size_t)s0 * D + rl * 8);
        float4 raw1 = *(const float4*)(H + (size_t)s1 * D + rl * 8);
        const __half2* h0 = (const __half2*)&raw0;
        const __half2* h1 = (const __half2*)&raw1;
        float2 f0 = __half22float2(h0[0]);
        float2 f1 = __half22float2(h0[1]);
        float2 f2 = __half22float2(h0[2]);
        float2 f3 = __half22float2(h0[3]);
        a0.x = fmaf(f0.x, c0, a0.x); a0.y = fmaf(f0.y, c0, a0.y);
        a1.x = fmaf(f1.x, c0, a1.x); a1.y = fmaf(f1.y, c0, a1.y);
        a2.x = fmaf(f2.x, c0, a2.x); a2.y = fmaf(f2.y, c0, a2.y);
        a3.x = fmaf(f3.x, c0, a3.x); a3.y = fmaf(f3.y, c0, a3.y);
        float2 g0 = __half22float2(h1[0]);
        float2 g1 = __half22float2(h1[1]);
        float2 g2 = __half22float2(h1[2]);
        float2 g3 = __half22float2(h1[3]);
        c0b.x = fmaf(g0.x, c1, c0b.x); c0b.y = fmaf(g0.y, c1, c0b.y);
        c1b.x = fmaf(g1.x, c1, c1b.x); c1b.y = fmaf(g1.y, c1, c1b.y);
        c2b.x = fmaf(g2.x, c1, c2b.x); c2b.y = fmaf(g2.y, c1, c2b.y);
        c3b.x = fmaf(g3.x, c1, c3b.x); c3b.y = fmaf(g3.y, c1, c3b.y);
    }
    a0.x += c0b.x; a0.y += c0b.y;
    a1.x += c1b.x; a1.y += c1b.y;
    a2.x += c2b.x; a2.y += c2b.y;
    a3.x += c3b.x; a3.y += c3b.y;

    // butterfly-reduce the 4 lane-groups (xor 16, 32)
    float v[8] = {a0.x, a0.y, a1.x, a1.y, a2.x, a2.y, a3.x, a3.y};
#pragma unroll
    for (int i = 0; i < 8; ++i) {
        v[i] += __shfl_xor(v[i], 16);
        v[i] += __shfl_xor(v[i], 32);
    }

    if (g == 0) {
        float s2 = dd * dd;
        float4 raw = *(const float4*)(H + (size_t)node * D + rl * 8);
        const __half2* hh = (const __half2*)&raw;
        float2 s0 = __half22float2(hh[0]);
        float2 s1 = __half22float2(hh[1]);
        float2 s2v = __half22float2(hh[2]);
        float2 s3 = __half22float2(hh[3]);
        float4 b0 = ((const float4*)b)[rl * 2];
        float4 b1v = ((const float4*)b)[rl * 2 + 1];
        float r[8];
        r[0] = fmaf(s0.x, s2, v[0] + b0.x);
        r[1] = fmaf(s0.y, s2, v[1] + b0.y);
        r[2] = fmaf(s1.x, s2, v[2] + b0.z);
        r[3] = fmaf(s1.y, s2, v[3] + b0.w);
        r[4] = fmaf(s2v.x, s2, v[4] + b1v.x);
        r[5] = fmaf(s2v.y, s2, v[5] + b1v.y);
        r[6] = fmaf(s3.x, s2, v[6] + b1v.z);
        r[7] = fmaf(s3.y, s2, v[7] + b1v.w);
        if (OUT_FP16) {
            __half* out = (__half*)outv;          // fp16 linear [NN][128]
            __half2 o[4];
            o[0] = __floats2half2_rn(r[0], r[1]);
            o[1] = __floats2half2_rn(r[2], r[3]);
            o[2] = __floats2half2_rn(r[4], r[5]);
            o[3] = __floats2half2_rn(r[6], r[7]);
            *(float4*)(out + (size_t)node * D + rl * 8) = *(float4*)o;
        } else {
            float* out = (float*)outv;            // fp32 linear [NN][128]
            float* op = out + (size_t)node * D + rl * 8;
            *(float4*)op = make_float4(r[0], r[1], r[2], r[3]);
            *(float4*)(op + 4) = make_float4(r[4], r[5], r[6], r[7]);
        }
    }
}

extern "C" void kernel_launch(void* const* d_in, const int* in_sizes, int n_in,
                              void* d_out, int out_size, void* d_ws, size_t ws_size,
                              hipStream_t stream) {
    const float* x  = (const float*)d_in[0];
    const int*   ei = (const int*)d_in[1];
    const float* W1 = (const float*)d_in[2];
    const float* b1 = (const float*)d_in[3];
    const float* W2 = (const float*)d_in[4];
    const float* b2 = (const float*)d_in[5];
    float* out = (float*)d_out;

    const int* src = ei;
    const int* dst = ei + NE;

    char* ws = (char*)d_ws;
    int*    cnt       = (int*)   (ws + 0);         // 200000 B
    int*    row_ptr   = (int*)   (ws + 204800);    // NN+1 ints
    int*    blockSums = (int*)   (ws + 409600);    // 784 B
    float*  dinv      = (float*) (ws + 410624);    // 200000 B
    char*   wimg1     = (char*)  (ws + 614400);    // 64 KB (fp16 hi+lo, swizzled)
    char*   wimg2     = (char*)  (ws + 679936);    // 64 KB
    unsigned short* rank = (unsigned short*)(ws + 745472);   // NE u16 = 1.6 MB
    unsigned short* csr  = (unsigned short*)(ws + 2345472);  // NE u16 = 1.6 MB
    __half* h         = (__half*)(ws + 3945472);   // [NN][128] fp16 = 12.8 MB
    __half* h2        = (__half*)(ws + 16745472);  // [NN][128] fp16 = 12.8 MB

    const int nBlkEdge = (NE + 255) / 256;   // 3125
    const int nBlkPull = NN / 4;             // 12500 (4 waves/block, 1 wave/node)

    // init (cnt zero + W prep) -> count -> scan -> [fill + gemm1] -> pull1 -> gemm2 -> pull2
    k_init<<<NBLK + 128, 256, 0, stream>>>(cnt, W1, W2, wimg1, wimg2);
    k_count<<<nBlkEdge, 256, 0, stream>>>(dst, cnt, rank);
    k_scan_partial<<<NBLK, 256, 0, stream>>>(cnt, blockSums);
    k_scan_final<<<NBLK, 256, 0, stream>>>(cnt, blockSums, row_ptr, dinv);
    k_fill_gemm1<<<NBLK_GEMM + nBlkEdge, 256, 0, stream>>>(src, dst, rank, row_ptr, csr, x, wimg1, h);
    k_pull<true><<<nBlkPull, 256, 0, stream>>>(h, dinv, b1, row_ptr, csr, h2);
    k_mgemm<true, true><<<NBLK_GEMM, 256, 0, stream>>>(h2, wimg2, h);
    k_pull<false><<<nBlkPull, 256, 0, stream>>>(h, dinv, b2, row_ptr, csr, out);
}

// Round 12
// 222.575 us; speedup vs baseline: 1.4176x; 1.0219x over previous
//
#include <hip/hip_runtime.h>
#include <hip/hip_fp16.h>

#define NN 50000
#define NE 800000
#define D 128
#define NBLK ((NN + 255) / 256)   // 196 blocks over nodes
#define NBLK_GEMM ((NN + 63) / 64) // 782

typedef __attribute__((ext_vector_type(8))) _Float16 f16x8;
typedef __attribute__((ext_vector_type(8))) short short8;
typedef __attribute__((ext_vector_type(4))) float f32x4;

// ---------------- init: zero cnt (blocks 0..195) + W prep (blocks 196..323) ----------------
// W prep: fp32 [k][n] -> swizzled fp16 image of W^T [n][k] (single image, 32 KB)
// byte offset of (n,k): (n*256 + k*2) ^ ((n&7)<<4)
__global__ __launch_bounds__(256) void k_init(int* __restrict__ cnt,
                                              const float* __restrict__ W1, const float* __restrict__ W2,
                                              char* __restrict__ img1, char* __restrict__ img2) {
    int b = blockIdx.x;
    if (b < NBLK) {
        int i = b * 256 + threadIdx.x;
        if (i < NN) cnt[i] = 0;
    } else {
        int pb = b - NBLK;  // 0..127
        const float* W = (pb < 64) ? W1 : W2;
        char* img = (pb < 64) ? img1 : img2;
        int e = (pb & 63) * 256 + threadIdx.x;  // 0..16383
        int k = e >> 7, n = e & 127;
        __half hi = __float2half_rn(W[e]);
        unsigned off = (unsigned)((n << 8) + (k << 1)) ^ (unsigned)((n & 7) << 4);
        *(__half*)(img + off) = hi;
    }
}

// ---------------- histogram + per-edge rank ----------------
__global__ __launch_bounds__(256) void k_count(const int* __restrict__ dst, int* __restrict__ cnt,
                                               unsigned short* __restrict__ rank) {
    int e = blockIdx.x * 256 + threadIdx.x;
    if (e < NE) rank[e] = (unsigned short)atomicAdd(&cnt[dst[e]], 1);
}

__global__ __launch_bounds__(256) void k_scan_partial(const int* __restrict__ cnt, int* __restrict__ blockSums) {
    __shared__ int s[256];
    int t = threadIdx.x;
    int i = blockIdx.x * 256 + t;
    s[t] = (i < NN) ? cnt[i] : 0;
    __syncthreads();
    for (int off = 128; off > 0; off >>= 1) {
        if (t < off) s[t] += s[t + off];
        __syncthreads();
    }
    if (t == 0) blockSums[blockIdx.x] = s[0];
}

// block offset computed in-kernel from blockSums; exclusive scan -> row_ptr; dinv = rsqrt(deg+1)
__global__ __launch_bounds__(256) void k_scan_final(const int* __restrict__ cnt, const int* __restrict__ blockSums,
                                                    int* __restrict__ row_ptr, float* __restrict__ dinv) {
    __shared__ int s[256];
    int t = threadIdx.x;

    // sum blockSums[0..blockIdx.x)
    s[t] = (t < NBLK && t < (int)blockIdx.x) ? blockSums[t] : 0;
    __syncthreads();
    for (int off = 128; off > 0; off >>= 1) {
        if (t < off) s[t] += s[t + off];
        __syncthreads();
    }
    int blockOff = s[0];
    __syncthreads();

    int i = blockIdx.x * 256 + t;
    int v = (i < NN) ? cnt[i] : 0;
    s[t] = v;
    __syncthreads();
    for (int off = 1; off < 256; off <<= 1) {
        int y = (t >= off) ? s[t - off] : 0;
        __syncthreads();
        s[t] += y;
        __syncthreads();
    }
    if (i < NN) {
        row_ptr[i] = s[t] - v + blockOff;
        dinv[i] = rsqrtf((float)v + 1.0f);
    }
    if (blockIdx.x == 0 && t == 0) row_ptr[NN] = NE;
}

// ---------------- GEMM core: H[M,128] = act(A[M,128]) @ W[128,128], fp16 MFMA, fp16 out ----------------
template <bool RELU_IN, bool A_FP16>
static __device__ __forceinline__ void gemm_core(char* lds, const void* __restrict__ Av,
                                                 const char* __restrict__ wimg, __half* __restrict__ H,
                                                 int bid, int t) {
    {   // stage swizzled fp16 W image (32 KB, byte-identical copy)
        const float4* gv = (const float4*)wimg;
        float4* lv = (float4*)lds;
#pragma unroll
        for (int i = 0; i < 8; ++i) lv[i * 256 + t] = gv[i * 256 + t];
    }
    __syncthreads();

    const int lane = t & 63;
    const int wv = t >> 6;
    const int r0 = bid * 64 + wv * 16;
    const int rl = lane & 15;              // A row in strip / C col
    const int g = lane >> 4;               // k-group 0..3
    int arow = r0 + rl;
    if (arow >= NN) arow = NN - 1;

    f32x4 acc[8];
#pragma unroll
    for (int j = 0; j < 8; ++j) acc[j] = (f32x4){0.f, 0.f, 0.f, 0.f};

#pragma unroll
    for (int ks = 0; ks < 4; ++ks) {
        f16x8 a;
        if (A_FP16) {
            const __half* A = (const __half*)Av;
            f32x4 raw = __builtin_nontemporal_load((const f32x4*)(A + (size_t)arow * D + ks * 32 + g * 8));
            if (RELU_IN) {
                short8 s = __builtin_bit_cast(short8, raw);
#pragma unroll
                for (int i = 0; i < 8; ++i) s[i] = (s[i] & (short)0x8000) ? (short)0 : s[i];
                a = __builtin_bit_cast(f16x8, s);
            } else {
                a = __builtin_bit_cast(f16x8, raw);
            }
        } else {
            const float* A = (const float*)Av;
            const float* ar = A + (size_t)arow * D + ks * 32 + g * 8;
            f32x4 p0 = __builtin_nontemporal_load((const f32x4*)ar);
            f32x4 p1 = __builtin_nontemporal_load((const f32x4*)(ar + 4));
            float av8[8] = {p0.x, p0.y, p0.z, p0.w, p1.x, p1.y, p1.z, p1.w};
#pragma unroll
            for (int i = 0; i < 8; ++i) {
                float f = RELU_IN ? fmaxf(av8[i], 0.f) : av8[i];
                a[i] = (_Float16)f;
            }
        }
        const int kofs = (ks * 32 + g * 8) << 1;   // byte offset of k within row
#pragma unroll
        for (int j = 0; j < 8; ++j) {
            int n = j * 16 + rl;
            unsigned off = (unsigned)((n << 8) + kofs) ^ (unsigned)((n & 7) << 4);
            f16x8 bh = *(const f16x8*)(lds + off);
            acc[j] = __builtin_amdgcn_mfma_f32_16x16x32_f16(a, bh, acc[j], 0, 0, 0);
        }
    }

    // C/D: col = lane&15 (+16j), row = (lane>>4)*4 + reg
#pragma unroll
    for (int j = 0; j < 8; ++j) {
#pragma unroll
        for (int i = 0; i < 4; ++i) {
            int row = r0 + g * 4 + i;
            if (row < NN) {
                unsigned short bits = __half_as_ushort(__float2half(acc[j][i]));
                __builtin_nontemporal_store(bits, (unsigned short*)(H + (size_t)row * D + j * 16 + rl));
            }
        }
    }
}

// ---------------- fused: gemm-1 (blocks 0..781) + CSR fill (blocks 782..) ----------------
__global__ __launch_bounds__(256) void k_fill_gemm1(const int* __restrict__ src, const int* __restrict__ dst,
                                                    const unsigned short* __restrict__ rank,
                                                    const int* __restrict__ row_ptr,
                                                    unsigned short* __restrict__ csr,
                                                    const float* __restrict__ x, const char* __restrict__ wimg,
                                                    __half* __restrict__ H) {
    __shared__ char lds[32768];
    int bid = blockIdx.x;
    if (bid < NBLK_GEMM) {
        gemm_core<false, false>(lds, x, wimg, H, bid, threadIdx.x);
    } else {
        int e = (bid - NBLK_GEMM) * 256 + threadIdx.x;
        if (e < NE) {
            int d = dst[e];
            csr[row_ptr[d] + rank[e]] = (unsigned short)src[e];
        }
    }
}

// standalone gemm for layer 2
template <bool RELU_IN, bool A_FP16>
__global__ __launch_bounds__(256) void k_mgemm(const void* __restrict__ Av, const char* __restrict__ wimg,
                                               __half* __restrict__ H) {
    __shared__ char lds[32768];
    gemm_core<RELU_IN, A_FP16>(lds, Av, wimg, H, blockIdx.x, threadIdx.x);
}

// ---------------- pull aggregation: one wave per node, 16 lanes per edge-row, 2-deep unroll ----------------
template <bool OUT_FP16>
__global__ __launch_bounds__(256) void k_pull(const __half* __restrict__ H, const float* __restrict__ dinv,
                                              const float* __restrict__ b, const int* __restrict__ row_ptr,
                                              const unsigned short* __restrict__ csr, void* __restrict__ outv) {
    int wid = (blockIdx.x * 256 + threadIdx.x) >> 6;
    int lane = threadIdx.x & 63;
    int node = __builtin_amdgcn_readfirstlane(wid);  // wave-uniform
    int rl = lane & 15;
    int g = lane >> 4;

    float dd = dinv[node];   // wave-uniform scalar

    float2 a0 = {0.f, 0.f}, a1 = {0.f, 0.f}, a2 = {0.f, 0.f}, a3 = {0.f, 0.f};
    float2 c0b = {0.f, 0.f}, c1b = {0.f, 0.f}, c2b = {0.f, 0.f}, c3b = {0.f, 0.f};

    int beg = row_ptr[node];
    int end = row_ptr[node + 1];
    for (int i = beg + g; i < end; i += 8) {
        int i1 = i + 4;
        bool ok = i1 < end;
        int s0 = csr[i];
        int s1 = csr[ok ? i1 : i];
        float c0 = dinv[s0] * dd;
        float c1 = ok ? dinv[s1] * dd : 0.f;
        float4 raw0 = *(const float4*)(H + (size_t)s0 * D + rl * 8);
        float4 raw1 = *(const float4*)(H + (size_t)s1 * D + rl * 8);
        const __half2* h0 = (const __half2*)&raw0;
        const __half2* h1 = (const __half2*)&raw1;
        float2 f0 = __half22float2(h0[0]);
        float2 f1 = __half22float2(h0[1]);
        float2 f2 = __half22float2(h0[2]);
        float2 f3 = __half22float2(h0[3]);
        a0.x = fmaf(f0.x, c0, a0.x); a0.y = fmaf(f0.y, c0, a0.y);
        a1.x = fmaf(f1.x, c0, a1.x); a1.y = fmaf(f1.y, c0, a1.y);
        a2.x = fmaf(f2.x, c0, a2.x); a2.y = fmaf(f2.y, c0, a2.y);
        a3.x = fmaf(f3.x, c0, a3.x); a3.y = fmaf(f3.y, c0, a3.y);
        float2 g0 = __half22float2(h1[0]);
        float2 g1 = __half22float2(h1[1]);
        float2 g2 = __half22float2(h1[2]);
        float2 g3 = __half22float2(h1[3]);
        c0b.x = fmaf(g0.x, c1, c0b.x); c0b.y = fmaf(g0.y, c1, c0b.y);
        c1b.x = fmaf(g1.x, c1, c1b.x); c1b.y = fmaf(g1.y, c1, c1b.y);
        c2b.x = fmaf(g2.x, c1, c2b.x); c2b.y = fmaf(g2.y, c1, c2b.y);
        c3b.x = fmaf(g3.x, c1, c3b.x); c3b.y = fmaf(g3.y, c1, c3b.y);
    }
    a0.x += c0b.x; a0.y += c0b.y;
    a1.x += c1b.x; a1.y += c1b.y;
    a2.x += c2b.x; a2.y += c2b.y;
    a3.x += c3b.x; a3.y += c3b.y;

    // butterfly-reduce the 4 lane-groups (xor 16, 32)
    float v[8] = {a0.x, a0.y, a1.x, a1.y, a2.x, a2.y, a3.x, a3.y};
#pragma unroll
    for (int i = 0; i < 8; ++i) {
        v[i] += __shfl_xor(v[i], 16);
        v[i] += __shfl_xor(v[i], 32);
    }

    if (g == 0) {
        float s2 = dd * dd;
        float4 raw = *(const float4*)(H + (size_t)node * D + rl * 8);
        const __half2* hh = (const __half2*)&raw;
        float2 s0 = __half22float2(hh[0]);
        float2 s1 = __half22float2(hh[1]);
        float2 s2v = __half22float2(hh[2]);
        float2 s3 = __half22float2(hh[3]);
        float4 b0 = ((const float4*)b)[rl * 2];
        float4 b1v = ((const float4*)b)[rl * 2 + 1];
        float r[8];
        r[0] = fmaf(s0.x, s2, v[0] + b0.x);
        r[1] = fmaf(s0.y, s2, v[1] + b0.y);
        r[2] = fmaf(s1.x, s2, v[2] + b0.z);
        r[3] = fmaf(s1.y, s2, v[3] + b0.w);
        r[4] = fmaf(s2v.x, s2, v[4] + b1v.x);
        r[5] = fmaf(s2v.y, s2, v[5] + b1v.y);
        r[6] = fmaf(s3.x, s2, v[6] + b1v.z);
        r[7] = fmaf(s3.y, s2, v[7] + b1v.w);
        if (OUT_FP16) {
            __half* out = (__half*)outv;          // fp16 linear [NN][128]
            __half2 o0 = __floats2half2_rn(r[0], r[1]);
            __half2 o1 = __floats2half2_rn(r[2], r[3]);
            __half2 o2 = __floats2half2_rn(r[4], r[5]);
            __half2 o3 = __floats2half2_rn(r[6], r[7]);
            f32x4 ov = {__builtin_bit_cast(float, o0), __builtin_bit_cast(float, o1),
                        __builtin_bit_cast(float, o2), __builtin_bit_cast(float, o3)};
            __builtin_nontemporal_store(ov, (f32x4*)(out + (size_t)node * D + rl * 8));
        } else {
            float* out = (float*)outv;            // fp32 linear [NN][128]
            float* op = out + (size_t)node * D + rl * 8;
            f32x4 r0v = {r[0], r[1], r[2], r[3]};
            f32x4 r1v = {r[4], r[5], r[6], r[7]};
            __builtin_nontemporal_store(r0v, (f32x4*)op);
            __builtin_nontemporal_store(r1v, (f32x4*)(op + 4));
        }
    }
}

extern "C" void kernel_launch(void* const* d_in, const int* in_sizes, int n_in,
                              void* d_out, int out_size, void* d_ws, size_t ws_size,
                              hipStream_t stream) {
    const float* x  = (const float*)d_in[0];
    const int*   ei = (const int*)d_in[1];
    const float* W1 = (const float*)d_in[2];
    const float* b1 = (const float*)d_in[3];
    const float* W2 = (const float*)d_in[4];
    const float* b2 = (const float*)d_in[5];
    float* out = (float*)d_out;

    const int* src = ei;
    const int* dst = ei + NE;

    char* ws = (char*)d_ws;
    int*    cnt       = (int*)   (ws + 0);         // 200000 B
    int*    row_ptr   = (int*)   (ws + 204800);    // NN+1 ints
    int*    blockSums = (int*)   (ws + 409600);    // 784 B
    float*  dinv      = (float*) (ws + 410624);    // 200000 B
    char*   wimg1     = (char*)  (ws + 614400);    // 32 KB (fp16, swizzled)
    char*   wimg2     = (char*)  (ws + 647168);    // 32 KB
    unsigned short* rank = (unsigned short*)(ws + 679936);   // NE u16 = 1.6 MB
    unsigned short* csr  = (unsigned short*)(ws + 2279936);  // NE u16 = 1.6 MB
    __half* h         = (__half*)(ws + 3879936);   // [NN][128] fp16 = 12.8 MB
    __half* h2        = (__half*)(ws + 16679936);  // [NN][128] fp16 = 12.8 MB

    const int nBlkEdge = (NE + 255) / 256;   // 3125
    const int nBlkPull = NN / 4;             // 12500 (4 waves/block, 1 wave/node)

    // init (cnt zero + W prep) -> count -> scan -> [fill + gemm1] -> pull1 -> gemm2 -> pull2
    k_init<<<NBLK + 128, 256, 0, stream>>>(cnt, W1, W2, wimg1, wimg2);
    k_count<<<nBlkEdge, 256, 0, stream>>>(dst, cnt, rank);
    k_scan_partial<<<NBLK, 256, 0, stream>>>(cnt, blockSums);
    k_scan_final<<<NBLK, 256, 0, stream>>>(cnt, blockSums, row_ptr, dinv);
    k_fill_gemm1<<<NBLK_GEMM + nBlkEdge, 256, 0, stream>>>(src, dst, rank, row_ptr, csr, x, wimg1, h);
    k_pull<true><<<nBlkPull, 256, 0, stream>>>(h, dinv, b1, row_ptr, csr, h2);
    k_mgemm<true, true><<<NBLK_GEMM, 256, 0, stream>>>(h2, wimg2, h);
    k_pull<false><<<nBlkPull, 256, 0, stream>>>(h, dinv, b2, row_ptr, csr, out);
}